// Round 1
// baseline (968.861 us; speedup 1.0000x reference)
//
#include <hip/hip_runtime.h>
#include <hip/hip_bf16.h>

#define LEAKY 0.1f

// ---------------------------------------------------------------------------
// conv1: 3->48, 3x3, pad 1, bias + LeakyReLU, no pool. H=W=256.
// Block: 256 threads = (wq 0..63, cog 0..3). Thread computes 4 w-pixels x 12 couts.
// Grid: (H, N)
// ---------------------------------------------------------------------------
__global__ __launch_bounds__(256) void conv1_k(const float* __restrict__ in,
                                               const float* __restrict__ wgt,
                                               const float* __restrict__ bias,
                                               float* __restrict__ out)
{
    const int H = 256, W = 256, CIN = 3;
    int h = blockIdx.x, n = blockIdx.y;
    int tid = threadIdx.x;
    int wq = tid & 63, cog = tid >> 6;      // 4 cout groups of 12
    int w0 = wq * 4;

    __shared__ float slds[3][3][260];       // [cin][row][w+1], w in -1..256
    __shared__ float wlds[3][48][12];       // [cin][cout][tap(9, padded 12)]

    for (int idx = tid; idx < CIN * 48 * 9; idx += 256) {
        int t = idx % 9;
        int rest = idx / 9;
        int ci = rest % CIN;
        int co = rest / CIN;
        wlds[ci][co][t] = wgt[(co * CIN + ci) * 9 + t];
    }
    for (int ci = 0; ci < CIN; ++ci) {
        for (int r = 0; r < 3; ++r) {
            int hh = h + r - 1;
            bool hv = (hh >= 0 && hh < H);
            const float* src = in + (((long)n * CIN + ci) * H + hh) * W;
            for (int j = tid; j < W + 2; j += 256) {
                int ww = j - 1;
                slds[ci][r][j] = (hv && ww >= 0 && ww < W) ? src[ww] : 0.f;
            }
        }
    }
    __syncthreads();

    float acc[12][4] = {};
    #pragma unroll
    for (int ci = 0; ci < CIN; ++ci) {
        float vin[3][6];
        #pragma unroll
        for (int r = 0; r < 3; ++r)
            #pragma unroll
            for (int c = 0; c < 6; ++c)
                vin[r][c] = slds[ci][r][w0 + c];
        #pragma unroll
        for (int k = 0; k < 12; ++k) {
            int co = cog * 12 + k;
            const float* wp9 = &wlds[ci][co][0];
            float4 wa = *(const float4*)wp9;
            float4 wb = *(const float4*)(wp9 + 4);
            float w8 = wp9[8];
            #pragma unroll
            for (int x = 0; x < 4; ++x) {
                acc[k][x] += vin[0][x] * wa.x + vin[0][x + 1] * wa.y + vin[0][x + 2] * wa.z
                           + vin[1][x] * wa.w + vin[1][x + 1] * wb.x + vin[1][x + 2] * wb.y
                           + vin[2][x] * wb.z + vin[2][x + 1] * wb.w + vin[2][x + 2] * w8;
            }
        }
    }

    #pragma unroll
    for (int k = 0; k < 12; ++k) {
        int co = cog * 12 + k;
        float bb = bias[co];
        float4 o;
        float* op = (float*)&o;
        #pragma unroll
        for (int x = 0; x < 4; ++x) {
            float v = acc[k][x] + bb;
            op[x] = v > 0.f ? v : LEAKY * v;
        }
        *(float4*)&out[(((long)n * 48 + co) * H + h) * W + w0] = o;
    }
}

// ---------------------------------------------------------------------------
// convpool: CIN->48, 3x3, pad 1, bias + LeakyReLU, then 2x2 maxpool.
// Block: 256 threads = (wp 0..PW-1, cog). Thread computes CPT couts x 2x2 patch,
// writes 1 pooled pixel per cout. Grid: (PH, N, 48/COB).
// ---------------------------------------------------------------------------
template<int CIN, int H, int W, int COB, int CHUNK>
__global__ __launch_bounds__(256) void convpool_k(const float* __restrict__ in,
                                                  const float* __restrict__ wgt,
                                                  const float* __restrict__ bias,
                                                  float* __restrict__ out)
{
    const int PW = W / 2, PH = H / 2;
    const int NCOG = 256 / PW;          // cout groups per block
    const int CPT = COB / NCOG;         // couts per thread
    const int LW = W + 4;               // padded LDS row stride

    int ph = blockIdx.x, n = blockIdx.y;
    int cob = blockIdx.z * COB;
    int tid = threadIdx.x;
    int wp = tid % PW, cog = tid / PW;
    int co0 = cog * CPT;                // local cout base within block's COB
    int h0 = 2 * ph;

    __shared__ float slds[CHUNK][4][LW];
    __shared__ float wlds[CHUNK][COB][12];

    float acc[CPT][2][2] = {};

    for (int cb = 0; cb < CIN; cb += CHUNK) {
        for (int idx = tid; idx < CHUNK * COB * 9; idx += 256) {
            int t = idx % 9;
            int rest = idx / 9;
            int co = rest % COB;
            int ci = rest / COB;
            wlds[ci][co][t] = wgt[((long)(cob + co) * CIN + cb + ci) * 9 + t];
        }
        for (int ci = 0; ci < CHUNK; ++ci) {
            #pragma unroll
            for (int r = 0; r < 4; ++r) {
                int hh = h0 + r - 1;
                bool hv = (hh >= 0 && hh < H);
                const float* src = in + (((long)n * CIN + cb + ci) * H + hh) * W;
                for (int j = tid; j < W + 2; j += 256) {
                    int ww = j - 1;
                    slds[ci][r][j] = (hv && ww >= 0 && ww < W) ? src[ww] : 0.f;
                }
            }
        }
        __syncthreads();

        #pragma unroll 1
        for (int ci = 0; ci < CHUNK; ++ci) {
            float vin[4][4];
            #pragma unroll
            for (int r = 0; r < 4; ++r)
                #pragma unroll
                for (int c = 0; c < 4; ++c)
                    vin[r][c] = slds[ci][r][2 * wp + c];
            #pragma unroll
            for (int k = 0; k < CPT; ++k) {
                const float* wp9 = &wlds[ci][co0 + k][0];
                float4 wa = *(const float4*)wp9;
                float4 wb = *(const float4*)(wp9 + 4);
                float w8 = wp9[8];
                #pragma unroll
                for (int dh = 0; dh < 2; ++dh)
                    #pragma unroll
                    for (int dw = 0; dw < 2; ++dw) {
                        acc[k][dh][dw] +=
                              vin[dh][dw]     * wa.x + vin[dh][dw + 1]     * wa.y + vin[dh][dw + 2]     * wa.z
                            + vin[dh + 1][dw] * wa.w + vin[dh + 1][dw + 1] * wb.x + vin[dh + 1][dw + 2] * wb.y
                            + vin[dh + 2][dw] * wb.z + vin[dh + 2][dw + 1] * wb.w + vin[dh + 2][dw + 2] * w8;
                    }
            }
        }
        __syncthreads();
    }

    #pragma unroll
    for (int k = 0; k < CPT; ++k) {
        int co = cob + co0 + k;
        float bb = bias[co];
        float m = -1e30f;
        #pragma unroll
        for (int dh = 0; dh < 2; ++dh)
            #pragma unroll
            for (int dw = 0; dw < 2; ++dw) {
                float v = acc[k][dh][dw] + bb;
                v = v > 0.f ? v : LEAKY * v;
                m = fmaxf(m, v);
            }
        out[(((long)n * 48 + co) * PH + ph) * PW + wp] = m;
    }
}

extern "C" void kernel_launch(void* const* d_in, const int* in_sizes, int n_in,
                              void* d_out, int out_size, void* d_ws, size_t ws_size,
                              hipStream_t stream)
{
    const float* x  = (const float*)d_in[0];
    const float* w1 = (const float*)d_in[1];
    const float* b1 = (const float*)d_in[2];
    const float* w2 = (const float*)d_in[3];
    const float* b2 = (const float*)d_in[4];
    const float* w3 = (const float*)d_in[5];
    const float* b3 = (const float*)d_in[6];
    const float* w4 = (const float*)d_in[7];
    const float* b4 = (const float*)d_in[8];

    float* A = (float*)d_ws;                 // conv1 out: 8*48*256*256 = 25,165,824 floats
    float* B = A + 25165824;                 // conv2 pooled out: 8*48*128*128 = 6,291,456 floats
    // conv3 pooled out reuses A (A dead after conv2): 8*48*64*64 = 1,572,864 floats
    float* outp = (float*)d_out;             // 8*48*32*32

    // conv1: 3->48 @256x256
    conv1_k<<<dim3(256, 8), 256, 0, stream>>>(x, w1, b1, A);
    // conv2: 48->48 @256x256 + pool -> 128x128   (cout split into 2 blocks of 24)
    convpool_k<48, 256, 256, 24, 8><<<dim3(128, 8, 2), 256, 0, stream>>>(A, w2, b2, B);
    // conv3: 48->48 @128x128 + pool -> 64x64
    convpool_k<48, 128, 128, 48, 8><<<dim3(64, 8, 1), 256, 0, stream>>>(B, w3, b3, A);
    // conv4: 48->48 @64x64 + pool -> 32x32
    convpool_k<48, 64, 64, 48, 8><<<dim3(32, 8, 1), 256, 0, stream>>>(A, w4, b4, outp);
}

// Round 2
// 93.867 us; speedup vs baseline: 10.3216x; 10.3216x over previous
//
#include <hip/hip_runtime.h>
#include <hip/hip_bf16.h>

typedef _Float16 half_t;
typedef _Float16 f16x8 __attribute__((ext_vector_type(8)));
typedef float f32x4 __attribute__((ext_vector_type(4)));

#define LEAKY 0.1f

// ===========================================================================
// Weight prep: conv1 -> [co][40] (k = (dr*3+ds)*3+ci, pad 27..39 = 0)
// ===========================================================================
__global__ __launch_bounds__(512) void prep_w1_k(const float* __restrict__ w,
                                                 half_t* __restrict__ wp)
{
    int t = blockIdx.x * 512 + threadIdx.x;
    if (t >= 48 * 40) return;
    int co = t / 40, kk = t % 40;
    float v = 0.f;
    if (kk < 27) {
        int ci = kk % 3, tap = kk / 3, dr = tap / 3, ds = tap % 3;
        v = w[((co * 3 + ci) * 3 + dr) * 3 + ds];
    }
    wp[t] = (half_t)v;
}

// conv2/3/4 -> [layer][10 taps][48 co][56 ci-pad]  (tap 9 = zeros, ci>=48 = 0)
__global__ __launch_bounds__(512) void prep_w234_k(const float* __restrict__ w2,
                                                   const float* __restrict__ w3,
                                                   const float* __restrict__ w4,
                                                   half_t* __restrict__ wp)
{
    int t = blockIdx.x * 512 + threadIdx.x;
    if (t >= 3 * 10 * 48 * 56) return;
    int layer = t / 26880;
    int r = t % 26880;
    int tap = r / 2688;
    int r2 = r % 2688;
    int co = r2 / 56, ci = r2 % 56;
    const float* src = layer == 0 ? w2 : (layer == 1 ? w3 : w4);
    float v = 0.f;
    if (tap < 9 && ci < 48) v = src[((co * 48 + ci) * 3 + tap / 3) * 3 + tap % 3];
    wp[t] = (half_t)v;
}

// ===========================================================================
// conv1 (3->48, 256x256, no pool) via MFMA + LDS im2col.
// Block: 512 thr = 8 waves; tile 16h x 32w. Wave handles 2h x 32w = 64 px.
// K = 27 pad 32 -> one 16x16x32 MFMA step. Out: NHWC fp16, ci padded to 56.
// ===========================================================================
__global__ __launch_bounds__(512) void conv1_mfma_k(const float* __restrict__ x,
                                                    const half_t* __restrict__ wp1,
                                                    const float* __restrict__ bias,
                                                    half_t* __restrict__ out)
{
    __shared__ alignas(16) half_t patch[512][40];   // [pixel][k-pad40] (80B stride)
    __shared__ alignas(16) half_t wlds[48][40];

    int tid = threadIdx.x;
    int n = blockIdx.z;
    int hblk = blockIdx.x * 16, wblk = blockIdx.y * 32;

    // stage weights: 3840 B = 240 uint4
    {
        const uint4* s = (const uint4*)wp1;
        uint4* d = (uint4*)&wlds[0][0];
        if (tid < 240) d[tid] = s[tid];
    }
    // im2col: thread t builds pixel (h_loc = t>>5, w_loc = t&31)
    {
        int hl = tid >> 5, wl = tid & 31;
        int gh = hblk + hl, gw = wblk + wl;
        half_t vals[32];
        #pragma unroll
        for (int dr = 0; dr < 3; ++dr)
            #pragma unroll
            for (int ds = 0; ds < 3; ++ds)
                #pragma unroll
                for (int ci = 0; ci < 3; ++ci) {
                    int hh = gh + dr - 1, ww = gw + ds - 1;
                    float v = (hh >= 0 && hh < 256 && ww >= 0 && ww < 256)
                              ? x[((n * 3 + ci) * 256 + hh) * 256 + ww] : 0.f;
                    vals[(dr * 3 + ds) * 3 + ci] = (half_t)v;
                }
        #pragma unroll
        for (int k = 27; k < 32; ++k) vals[k] = (half_t)0.f;
        uint4* d = (uint4*)&patch[tid][0];
        const uint4* s = (const uint4*)vals;
        d[0] = s[0]; d[1] = s[1]; d[2] = s[2]; d[3] = s[3];
    }
    __syncthreads();

    int lane = tid & 63, wave = tid >> 6;
    int m = lane & 15, g = lane >> 4;
    int hpar = m & 1, wloc = m >> 1;

    const char* pb = (const char*)&patch[0][0];
    const char* wb = (const char*)&wlds[0][0];

    f16x8 bfr[3], afr[4];
    #pragma unroll
    for (int nt = 0; nt < 3; ++nt)
        bfr[nt] = *(const f16x8*)(wb + (nt * 16 + m) * 80 + g * 16);
    #pragma unroll
    for (int mt = 0; mt < 4; ++mt)
        afr[mt] = *(const f16x8*)(pb + ((2 * wave + hpar) * 32 + mt * 8 + wloc) * 80 + g * 16);

    f32x4 acc[4][3];
    #pragma unroll
    for (int mt = 0; mt < 4; ++mt)
        #pragma unroll
        for (int nt = 0; nt < 3; ++nt) {
            f32x4 z = {0.f, 0.f, 0.f, 0.f};
            acc[mt][nt] = __builtin_amdgcn_mfma_f32_16x16x32_f16(afr[mt], bfr[nt], z, 0, 0, 0);
        }

    // epilogue: bias + leaky, write NHWC-pad56 fp16
    #pragma unroll
    for (int nt = 0; nt < 3; ++nt) {
        int co = nt * 16 + m;
        float bb = bias[co];
        #pragma unroll
        for (int mt = 0; mt < 4; ++mt) {
            #pragma unroll
            for (int j = 0; j < 4; ++j) {
                float v = acc[mt][nt][j] + bb;
                v = v > 0.f ? v : LEAKY * v;
                int h = hblk + 2 * wave + (j & 1);
                int w = wblk + mt * 8 + 2 * g + (j >> 1);
                out[((n * 256 + h) * 256 + w) * 56 + co] = (half_t)v;
            }
        }
    }
}

// ===========================================================================
// convpool (48->48, HxW, 3x3 pad1 + bias + leaky + 2x2 maxpool) via MFMA.
// Block: 512 thr = 8 waves; tile 16 in-rows x WCHUNK w. Wave = 1 h-pair.
// M = WCHUNK*2 px (m = (w<<1)|hpar), N = 48, K = 9*48=432 pad 448 (14 steps).
// Lane's 4 C regs = full 2x2 pool window.
// Input: NHWC-pad56 fp16. Output: same (or fp32 NCHW if FINAL).
// ===========================================================================
template<int H, int W, int WCHUNK, bool FINAL>
__global__ __launch_bounds__(512) void convpool_mfma_k(const half_t* __restrict__ in,
                                                       const half_t* __restrict__ wp,
                                                       const float* __restrict__ bias,
                                                       void* __restrict__ outv)
{
    constexpr int TCOLS = WCHUNK + 2;
    constexpr int MT = WCHUNK / 8;
    constexpr int HO = H / 2, WO = W / 2;

    __shared__ alignas(16) half_t in_t[18][TCOLS][56];    // 112 B / pixel
    __shared__ alignas(16) half_t wt[10 * 48 * 56];       // [tap][co][ci-pad]

    int tid = threadIdx.x;
    int n = blockIdx.z;
    int hblk = blockIdx.x * 16, wblk = blockIdx.y * WCHUNK;

    // ---- stage weights: 26880 halfs = 3360 uint4 ----
    {
        const uint4* s = (const uint4*)wp;
        uint4* d = (uint4*)&wt[0];
        for (int c = tid; c < 3360; c += 512) d[c] = s[c];
    }
    // ---- stage input tile: rows hblk-1..hblk+16, pix wblk-1..wblk+WCHUNK ----
    {
        const uint4* s = (const uint4*)in;
        uint4* d = (uint4*)&in_t[0][0][0];
        constexpr int CH = 18 * TCOLS * 7;
        for (int c = tid; c < CH; c += 512) {
            int row = c / (TCOLS * 7);
            int rem = c - row * (TCOLS * 7);
            int pix = rem / 7;
            int sub = rem - pix * 7;
            int gh = hblk - 1 + row, gw = wblk - 1 + pix;
            uint4 v = {0u, 0u, 0u, 0u};
            if ((unsigned)gh < (unsigned)H && (unsigned)gw < (unsigned)W)
                v = s[((n * H + gh) * W + gw) * 7 + sub];
            d[c] = v;
        }
    }
    __syncthreads();

    int lane = tid & 63, hp = tid >> 6;     // wave = h-pair
    int m = lane & 15, g = lane >> 4;
    int hpar = m & 1, wloc = m >> 1;
    int abase = 2 * hp * TCOLS * 112;

    // per-lane per-step LDS byte offsets (k-chunk kc = 4*s + g)
    int aoff[14], boff[14];
    #pragma unroll
    for (int s = 0; s < 14; ++s) {
        int kc = 4 * s + g;
        int tap = kc / 6;
        int ci8 = kc - tap * 6;
        int dr = tap / 3, ds = tap - dr * 3;
        if (tap == 9) { dr = 0; ds = 0; }        // B-side is zeros; A addr just valid
        aoff[s] = ((hpar + dr) * TCOLS + (wloc + ds)) * 112 + ci8 * 16;
        boff[s] = tap * 5376 + m * 112 + ci8 * 16;
    }

    const char* ib = (const char*)&in_t[0][0][0];
    const char* wb = (const char*)&wt[0];

    f32x4 acc[MT][3];
    #pragma unroll
    for (int mt = 0; mt < MT; ++mt)
        #pragma unroll
        for (int nt = 0; nt < 3; ++nt)
            acc[mt][nt] = (f32x4){0.f, 0.f, 0.f, 0.f};

    #pragma unroll
    for (int s = 0; s < 14; ++s) {
        f16x8 b0 = *(const f16x8*)(wb + boff[s]);
        f16x8 b1 = *(const f16x8*)(wb + boff[s] + 1792);
        f16x8 b2 = *(const f16x8*)(wb + boff[s] + 3584);
        f16x8 a[MT];
        #pragma unroll
        for (int mt = 0; mt < MT; ++mt)
            a[mt] = *(const f16x8*)(ib + abase + aoff[s] + mt * 896);
        #pragma unroll
        for (int mt = 0; mt < MT; ++mt) {
            acc[mt][0] = __builtin_amdgcn_mfma_f32_16x16x32_f16(a[mt], b0, acc[mt][0], 0, 0, 0);
            acc[mt][1] = __builtin_amdgcn_mfma_f32_16x16x32_f16(a[mt], b1, acc[mt][1], 0, 0, 0);
            acc[mt][2] = __builtin_amdgcn_mfma_f32_16x16x32_f16(a[mt], b2, acc[mt][2], 0, 0, 0);
        }
    }

    // ---- epilogue: bias + leaky + 2x2 maxpool (within-lane) ----
    int hq = blockIdx.x * 8 + hp;               // pooled row
    #pragma unroll
    for (int nt = 0; nt < 3; ++nt) {
        int co = nt * 16 + m;
        float bb = bias[co];
        #pragma unroll
        for (int mt = 0; mt < MT; ++mt) {
            float p = -1e30f;
            #pragma unroll
            for (int j = 0; j < 4; ++j) {
                float v = acc[mt][nt][j] + bb;
                v = v > 0.f ? v : LEAKY * v;
                p = fmaxf(p, v);
            }
            int wq = blockIdx.y * (WCHUNK / 2) + mt * 4 + g;   // pooled col
            if (FINAL)
                ((float*)outv)[(((long)n * 48 + co) * HO + hq) * WO + wq] = p;
            else
                ((half_t*)outv)[((n * HO + hq) * WO + wq) * 56 + co] = (half_t)p;
        }
    }
}

// ===========================================================================
extern "C" void kernel_launch(void* const* d_in, const int* in_sizes, int n_in,
                              void* d_out, int out_size, void* d_ws, size_t ws_size,
                              hipStream_t stream)
{
    const float* x  = (const float*)d_in[0];
    const float* w1 = (const float*)d_in[1];
    const float* b1 = (const float*)d_in[2];
    const float* w2 = (const float*)d_in[3];
    const float* b2 = (const float*)d_in[4];
    const float* w3 = (const float*)d_in[5];
    const float* b3 = (const float*)d_in[6];
    const float* w4 = (const float*)d_in[7];
    const float* b4 = (const float*)d_in[8];

    half_t* Wb = (half_t*)d_ws;
    half_t* wp1  = Wb;                 // 1920 halfs
    half_t* wp2  = Wb + 2048;          // 26880
    half_t* wp3  = Wb + 28928;         // 26880
    half_t* wp4  = Wb + 55808;         // 26880
    half_t* act1 = Wb + 90112;         // 8*256*256*56 = 29360128
    half_t* act2 = Wb + 29450240;      // 8*128*128*56 = 7340032
    half_t* act3 = Wb + 36790272;      // 8*64*64*56   = 1835008

    prep_w1_k<<<dim3(4), 512, 0, stream>>>(w1, wp1);
    prep_w234_k<<<dim3(158), 512, 0, stream>>>(w2, w3, w4, wp2);

    // conv1: 3->48 @256x256
    conv1_mfma_k<<<dim3(16, 8, 8), 512, 0, stream>>>(x, wp1, b1, act1);
    // conv2: 48->48 @256 + pool -> 128
    convpool_mfma_k<256, 256, 32, false><<<dim3(16, 8, 8), 512, 0, stream>>>(act1, wp2, b2, act2);
    // conv3: 48->48 @128 + pool -> 64
    convpool_mfma_k<128, 128, 32, false><<<dim3(8, 4, 8), 512, 0, stream>>>(act2, wp3, b3, act3);
    // conv4: 48->48 @64 + pool -> 32, fp32 NCHW out
    convpool_mfma_k<64, 64, 16, true><<<dim3(4, 4, 8), 512, 0, stream>>>(act3, wp4, b4, d_out);
}

// Round 3
// 88.700 us; speedup vs baseline: 10.9229x; 1.0583x over previous
//
#include <hip/hip_runtime.h>
#include <hip/hip_bf16.h>

typedef _Float16 half_t;
typedef _Float16 f16x8 __attribute__((ext_vector_type(8)));
typedef float f32x4 __attribute__((ext_vector_type(4)));

#define LEAKY 0.1f

// ===========================================================================
// Weight prep: conv1 -> [co][40] (k = (dr*3+ds)*3+ci, pad 27..39 = 0)
// ===========================================================================
__global__ __launch_bounds__(512) void prep_w1_k(const float* __restrict__ w,
                                                 half_t* __restrict__ wp)
{
    int t = blockIdx.x * 512 + threadIdx.x;
    if (t >= 48 * 40) return;
    int co = t / 40, kk = t % 40;
    float v = 0.f;
    if (kk < 27) {
        int ci = kk % 3, tap = kk / 3, dr = tap / 3, ds = tap % 3;
        v = w[((co * 3 + ci) * 3 + dr) * 3 + ds];
    }
    wp[t] = (half_t)v;
}

// conv2/3/4 -> [layer][phase(2)][tap(10)][co(48)][ci(24)]; tap 9 = zeros.
// Per-layer stride 46080 halfs; per-phase 11520.
__global__ __launch_bounds__(512) void prep_w234_k(const float* __restrict__ w2,
                                                   const float* __restrict__ w3,
                                                   const float* __restrict__ w4,
                                                   half_t* __restrict__ wp)
{
    int t = blockIdx.x * 512 + threadIdx.x;
    if (t >= 3 * 46080) return;
    int layer = t / 46080;
    int r = t % 46080;
    int phase = r / 11520;
    int r2 = r % 11520;
    int tap = r2 / 1152;
    int r3 = r2 % 1152;
    int co = r3 / 24, ci = r3 % 24;
    const float* src = layer == 0 ? w2 : (layer == 1 ? w3 : w4);
    float v = 0.f;
    if (tap < 9) {
        int cig = phase * 24 + ci;
        v = src[((co * 48 + cig) * 3 + tap / 3) * 3 + tap % 3];
    }
    wp[t] = (half_t)v;
}

// ===========================================================================
// conv1 (3->48, 256x256, no pool) via MFMA + LDS im2col.
// Block: 512 thr = 8 waves; tile 16h x 32w. Out: NHWC fp16, ci padded to 48.
// ===========================================================================
__global__ __launch_bounds__(512) void conv1_mfma_k(const float* __restrict__ x,
                                                    const half_t* __restrict__ wp1,
                                                    const float* __restrict__ bias,
                                                    half_t* __restrict__ out)
{
    __shared__ alignas(16) half_t patch[512][40];   // [pixel][k-pad40] (80B stride)
    __shared__ alignas(16) half_t wlds[48][40];

    int tid = threadIdx.x;
    int n = blockIdx.z;
    int hblk = blockIdx.x * 16, wblk = blockIdx.y * 32;

    {
        const uint4* s = (const uint4*)wp1;
        uint4* d = (uint4*)&wlds[0][0];
        if (tid < 240) d[tid] = s[tid];
    }
    {
        int hl = tid >> 5, wl = tid & 31;
        int gh = hblk + hl, gw = wblk + wl;
        half_t vals[32];
        #pragma unroll
        for (int dr = 0; dr < 3; ++dr)
            #pragma unroll
            for (int ds = 0; ds < 3; ++ds)
                #pragma unroll
                for (int ci = 0; ci < 3; ++ci) {
                    int hh = gh + dr - 1, ww = gw + ds - 1;
                    float v = (hh >= 0 && hh < 256 && ww >= 0 && ww < 256)
                              ? x[((n * 3 + ci) * 256 + hh) * 256 + ww] : 0.f;
                    vals[(dr * 3 + ds) * 3 + ci] = (half_t)v;
                }
        #pragma unroll
        for (int k = 27; k < 32; ++k) vals[k] = (half_t)0.f;
        uint4* d = (uint4*)&patch[tid][0];
        const uint4* s = (const uint4*)vals;
        d[0] = s[0]; d[1] = s[1]; d[2] = s[2]; d[3] = s[3];
    }
    __syncthreads();

    int lane = tid & 63, wave = tid >> 6;
    int m = lane & 15, g = lane >> 4;
    int hpar = m & 1, wloc = m >> 1;

    const char* pb = (const char*)&patch[0][0];
    const char* wb = (const char*)&wlds[0][0];

    f16x8 bfr[3], afr[4];
    #pragma unroll
    for (int nt = 0; nt < 3; ++nt)
        bfr[nt] = *(const f16x8*)(wb + (nt * 16 + m) * 80 + g * 16);
    #pragma unroll
    for (int mt = 0; mt < 4; ++mt)
        afr[mt] = *(const f16x8*)(pb + ((2 * wave + hpar) * 32 + mt * 8 + wloc) * 80 + g * 16);

    f32x4 acc[4][3];
    #pragma unroll
    for (int mt = 0; mt < 4; ++mt)
        #pragma unroll
        for (int nt = 0; nt < 3; ++nt) {
            f32x4 z = {0.f, 0.f, 0.f, 0.f};
            acc[mt][nt] = __builtin_amdgcn_mfma_f32_16x16x32_f16(afr[mt], bfr[nt], z, 0, 0, 0);
        }

    #pragma unroll
    for (int nt = 0; nt < 3; ++nt) {
        int co = nt * 16 + m;
        float bb = bias[co];
        #pragma unroll
        for (int mt = 0; mt < 4; ++mt) {
            #pragma unroll
            for (int j = 0; j < 4; ++j) {
                float v = acc[mt][nt][j] + bb;
                v = v > 0.f ? v : LEAKY * v;
                int h = hblk + 2 * wave + (j & 1);
                int w = wblk + mt * 8 + 2 * g + (j >> 1);
                out[((n * 256 + h) * 256 + w) * 48 + co] = (half_t)v;
            }
        }
    }
}

// ===========================================================================
// convpool2 (48->48, 3x3 pad1 + bias + leaky + 2x2 maxpool), ci-split K.
// Block: 256 thr = 4 waves; tile 8 input rows x 32 w. Wave = 1 h-pair x 32 w.
// Two phases: ci 0..23 then 24..47; each re-stages input (NHWC-48) + weights.
// LDS = 39.4 KB -> 4 blocks/CU. M-lane m = (w<<1)|hpar; lane's 4 C regs =
// 2x2 pool window. K per phase = 9 taps x 24 ci = 27 chunks + 1 zero = 7 steps.
// ===========================================================================
template<int H, int W, bool FINAL>
__global__ __launch_bounds__(256, 4) void convpool2_k(const half_t* __restrict__ in,
                                                      const half_t* __restrict__ wp,
                                                      const float* __restrict__ bias,
                                                      void* __restrict__ outv)
{
    constexpr int HO = H / 2, WO = W / 2;

    __shared__ alignas(16) half_t in_t[10][34][24];   // 48 B / pixel-phase
    __shared__ alignas(16) half_t wt[10][48][24];     // [tap][co][ci24]

    int tid = threadIdx.x;
    int n = blockIdx.z;
    int hblk = blockIdx.x * 8, wblk = blockIdx.y * 32;
    int lane = tid & 63, hp = tid >> 6;     // wave = h-pair (0..3)
    int m = lane & 15, g = lane >> 4;
    int hpar = m & 1, wloc = m >> 1;

    // per-lane per-step LDS byte offsets (k-chunk kc = 4*s + g), same both phases
    int aoff[7], boff[7];
    #pragma unroll
    for (int s = 0; s < 7; ++s) {
        int kc = 4 * s + g;
        int tap = kc / 3, ci8 = kc - tap * 3;
        int dr = tap / 3, ds = tap - dr * 3;
        if (tap == 9) { dr = 0; ds = 0; }          // B-side zeros; A addr just valid
        aoff[s] = ((hpar + dr) * 34 + (wloc + ds)) * 48 + ci8 * 16;
        boff[s] = (tap * 48 + m) * 48 + ci8 * 16;
    }
    int abase = hp * 3264;                          // 2*hp rows * 34 pix * 48 B

    const char* ib = (const char*)&in_t[0][0][0];
    const char* wb = (const char*)&wt[0][0][0];

    f32x4 acc[4][3];
    #pragma unroll
    for (int mt = 0; mt < 4; ++mt)
        #pragma unroll
        for (int nt = 0; nt < 3; ++nt)
            acc[mt][nt] = (f32x4){0.f, 0.f, 0.f, 0.f};

    for (int p = 0; p < 2; ++p) {
        // stage weights for this ci-half: linear 1440 uint4
        {
            const uint4* s4 = (const uint4*)(wp + p * 11520);
            uint4* d = (uint4*)&wt[0][0][0];
            for (int c = tid; c < 1440; c += 256) d[c] = s4[c];
        }
        // stage input tile for this ci-half: rows hblk-1..hblk+8, pix wblk-1..wblk+32
        {
            const uint4* s4 = (const uint4*)in;
            uint4* d = (uint4*)&in_t[0][0][0];
            for (int c = tid; c < 1020; c += 256) {
                int row = c / 102;
                int rem = c - row * 102;
                int pix = rem / 3;
                int sub = rem - pix * 3;
                int gh = hblk - 1 + row, gw = wblk - 1 + pix;
                uint4 v = {0u, 0u, 0u, 0u};
                if ((unsigned)gh < (unsigned)H && (unsigned)gw < (unsigned)W)
                    v = s4[((n * H + gh) * W + gw) * 6 + p * 3 + sub];
                d[c] = v;
            }
        }
        __syncthreads();

        #pragma unroll
        for (int s = 0; s < 7; ++s) {
            f16x8 b0 = *(const f16x8*)(wb + boff[s]);
            f16x8 b1 = *(const f16x8*)(wb + boff[s] + 768);
            f16x8 b2 = *(const f16x8*)(wb + boff[s] + 1536);
            f16x8 a[4];
            #pragma unroll
            for (int mt = 0; mt < 4; ++mt)
                a[mt] = *(const f16x8*)(ib + abase + aoff[s] + mt * 384);
            __builtin_amdgcn_s_setprio(1);
            #pragma unroll
            for (int mt = 0; mt < 4; ++mt) {
                acc[mt][0] = __builtin_amdgcn_mfma_f32_16x16x32_f16(a[mt], b0, acc[mt][0], 0, 0, 0);
                acc[mt][1] = __builtin_amdgcn_mfma_f32_16x16x32_f16(a[mt], b1, acc[mt][1], 0, 0, 0);
                acc[mt][2] = __builtin_amdgcn_mfma_f32_16x16x32_f16(a[mt], b2, acc[mt][2], 0, 0, 0);
            }
            __builtin_amdgcn_s_setprio(0);
        }
        __syncthreads();
    }

    // ---- epilogue: bias + leaky + 2x2 maxpool (within-lane) ----
    int hq = blockIdx.x * 4 + hp;                   // pooled row
    #pragma unroll
    for (int nt = 0; nt < 3; ++nt) {
        int co = nt * 16 + m;
        float bb = bias[co];
        #pragma unroll
        for (int mt = 0; mt < 4; ++mt) {
            float pmax = -1e30f;
            #pragma unroll
            for (int j = 0; j < 4; ++j) {
                float v = acc[mt][nt][j] + bb;
                v = v > 0.f ? v : LEAKY * v;
                pmax = fmaxf(pmax, v);
            }
            int wq = blockIdx.y * 16 + mt * 4 + g;  // pooled col
            if (FINAL)
                ((float*)outv)[(((long)n * 48 + co) * HO + hq) * WO + wq] = pmax;
            else
                ((half_t*)outv)[((n * HO + hq) * WO + wq) * 48 + co] = (half_t)pmax;
        }
    }
}

// ===========================================================================
extern "C" void kernel_launch(void* const* d_in, const int* in_sizes, int n_in,
                              void* d_out, int out_size, void* d_ws, size_t ws_size,
                              hipStream_t stream)
{
    const float* x  = (const float*)d_in[0];
    const float* w1 = (const float*)d_in[1];
    const float* b1 = (const float*)d_in[2];
    const float* w2 = (const float*)d_in[3];
    const float* b2 = (const float*)d_in[4];
    const float* w3 = (const float*)d_in[5];
    const float* b3 = (const float*)d_in[6];
    const float* w4 = (const float*)d_in[7];
    const float* b4 = (const float*)d_in[8];

    half_t* Wb = (half_t*)d_ws;
    half_t* wp1  = Wb;                      // 1920 halfs (pad to 2048)
    half_t* wp2  = Wb + 2048;               // 46080 per layer
    half_t* wp3  = wp2 + 46080;
    half_t* wp4  = wp3 + 46080;
    half_t* act1 = Wb + 140288;             // 8*256*256*48 = 25165824
    half_t* act2 = act1 + 25165824;         // 8*128*128*48 = 6291456
    half_t* act3 = act2 + 6291456;          // 8*64*64*48   = 1572864

    prep_w1_k<<<dim3(4), 512, 0, stream>>>(w1, wp1);
    prep_w234_k<<<dim3(270), 512, 0, stream>>>(w2, w3, w4, wp2);

    // conv1: 3->48 @256x256
    conv1_mfma_k<<<dim3(16, 8, 8), 512, 0, stream>>>(x, wp1, b1, act1);
    // conv2: 48->48 @256 + pool -> 128
    convpool2_k<256, 256, false><<<dim3(32, 8, 8), 256, 0, stream>>>(act1, wp2, b2, act2);
    // conv3: 48->48 @128 + pool -> 64
    convpool2_k<128, 128, false><<<dim3(16, 4, 8), 256, 0, stream>>>(act2, wp3, b3, act3);
    // conv4: 48->48 @64 + pool -> 32, fp32 NCHW out
    convpool2_k<64, 64, true><<<dim3(8, 2, 8), 256, 0, stream>>>(act3, wp4, b4, d_out);
}

// Round 4
// 77.286 us; speedup vs baseline: 12.5360x; 1.1477x over previous
//
#include <hip/hip_runtime.h>
#include <hip/hip_bf16.h>

typedef _Float16 half_t;
typedef _Float16 f16x8 __attribute__((ext_vector_type(8)));
typedef float f32x4 __attribute__((ext_vector_type(4)));

#define LEAKY 0.1f

// ===========================================================================
// Combined weight prep.
//  wp1: [co(48)][40]  k = (dr*3+ds)*3+ci, pad 27..39 = 0           (1920 h)
//  wp234: [layer(3)][tap(10)][co(48)][ci(48)], tap 9 = zeros       (69120 h)
// ===========================================================================
__global__ __launch_bounds__(512) void prep_w_k(const float* __restrict__ w1,
                                                const float* __restrict__ w2,
                                                const float* __restrict__ w3,
                                                const float* __restrict__ w4,
                                                half_t* __restrict__ wp1,
                                                half_t* __restrict__ wp234)
{
    int t = blockIdx.x * 512 + threadIdx.x;
    if (t < 1920) {
        int co = t / 40, kk = t % 40;
        float v = 0.f;
        if (kk < 27) {
            int ci = kk % 3, tap = kk / 3, dr = tap / 3, ds = tap % 3;
            v = w1[((co * 3 + ci) * 3 + dr) * 3 + ds];
        }
        wp1[t] = (half_t)v;
        return;
    }
    int t2 = t - 1920;
    if (t2 >= 3 * 23040) return;
    int layer = t2 / 23040;
    int r = t2 % 23040;
    int tap = r / 2304;
    int r2 = r % 2304;
    int co = r2 / 48, ci = r2 % 48;
    const float* src = layer == 0 ? w2 : (layer == 1 ? w3 : w4);
    float v = 0.f;
    if (tap < 9) v = src[((co * 48 + ci) * 3 + tap / 3) * 3 + tap % 3];
    wp234[t2] = (half_t)v;
}

// ===========================================================================
// conv1 (3->48, 256x256, no pool) via MFMA; x-tile staged in LDS.
// Block: 512 thr = 8 waves; tile 16h x 32w. Out: NHWC-48 fp16.
// ===========================================================================
__global__ __launch_bounds__(512) void conv1_mfma_k(const float* __restrict__ x,
                                                    const half_t* __restrict__ wp1,
                                                    const float* __restrict__ bias,
                                                    half_t* __restrict__ out)
{
    __shared__ alignas(16) half_t xt[3][18][36];    // rows hblk-1.., cols wblk-1..
    __shared__ alignas(16) half_t wlds[48][40];

    int tid = threadIdx.x;
    int n = blockIdx.z;
    int hblk = blockIdx.x * 16, wblk = blockIdx.y * 32;

    {
        const uint4* s = (const uint4*)wp1;
        uint4* d = (uint4*)&wlds[0][0];
        if (tid < 240) d[tid] = s[tid];
    }
    for (int c = tid; c < 3 * 18 * 34; c += 512) {
        int ci = c / 612, rem = c % 612;
        int row = rem / 34, col = rem % 34;
        int gh = hblk - 1 + row, gw = wblk - 1 + col;
        float v = 0.f;
        if ((unsigned)gh < 256u && (unsigned)gw < 256u)
            v = x[((n * 3 + ci) * 256 + gh) * 256 + gw];
        xt[ci][row][col] = (half_t)v;
    }
    __syncthreads();

    int lane = tid & 63, wave = tid >> 6;
    int m = lane & 15, g = lane >> 4;
    int hpar = m & 1, wloc = m >> 1;
    int row0 = 2 * wave + hpar;

    // build A fragments directly from xt: elem j of frag mt has k = g*8+j
    f16x8 afr[4];
    #pragma unroll
    for (int j = 0; j < 8; ++j) {
        int k = g * 8 + j;
        int tap = k / 3, ci = k - 3 * tap;
        int dr = tap / 3, ds = tap - 3 * dr;
        bool valid = k < 27;
        #pragma unroll
        for (int mt = 0; mt < 4; ++mt) {
            half_t v = (half_t)0.f;
            if (valid) v = xt[ci][row0 + dr][mt * 8 + wloc + ds];
            afr[mt][j] = v;
        }
    }

    const char* wb = (const char*)&wlds[0][0];
    f16x8 bfr[3];
    #pragma unroll
    for (int nt = 0; nt < 3; ++nt)
        bfr[nt] = *(const f16x8*)(wb + (nt * 16 + m) * 80 + g * 16);

    f32x4 acc[4][3];
    #pragma unroll
    for (int mt = 0; mt < 4; ++mt)
        #pragma unroll
        for (int nt = 0; nt < 3; ++nt) {
            f32x4 z = {0.f, 0.f, 0.f, 0.f};
            acc[mt][nt] = __builtin_amdgcn_mfma_f32_16x16x32_f16(afr[mt], bfr[nt], z, 0, 0, 0);
        }

    #pragma unroll
    for (int nt = 0; nt < 3; ++nt) {
        int co = nt * 16 + m;
        float bb = bias[co];
        #pragma unroll
        for (int mt = 0; mt < 4; ++mt) {
            #pragma unroll
            for (int j = 0; j < 4; ++j) {
                float v = acc[mt][nt][j] + bb;
                v = v > 0.f ? v : LEAKY * v;
                int h = hblk + 2 * wave + (j & 1);
                int w = wblk + mt * 8 + 2 * g + (j >> 1);
                out[((n * 256 + h) * 256 + w) * 48 + co] = (half_t)v;
            }
        }
    }
}

// ===========================================================================
// convpool (48->48, 3x3 pad1 + bias + leaky + 2x2 maxpool), single-phase K.
// Block: 256 thr = 4 waves; tile 8 input rows x 32 w. Wave = 1 h-pair.
// A: LDS in_t[10][34][56-pad] (112 B/pixel -> conflict-free b128 reads).
// B: direct from global (L2-resident, no LDS staging).
// K = tap*48+ci, 432 real, padded to 448 (tap 9 zeros) = 14 steps.
// ===========================================================================
template<int H, int W, bool FINAL>
__global__ __launch_bounds__(256, 4) void convpool3_k(const half_t* __restrict__ in,
                                                      const half_t* __restrict__ wp,
                                                      const float* __restrict__ bias,
                                                      void* __restrict__ outv)
{
    constexpr int HO = H / 2, WO = W / 2;

    __shared__ alignas(16) half_t in_t[10][34][56];   // 38.1 KB

    int tid = threadIdx.x;
    int n = blockIdx.z;
    int hblk = blockIdx.x * 8, wblk = blockIdx.y * 32;
    int lane = tid & 63, hp = tid >> 6;     // wave = h-pair (0..3)
    int m = lane & 15, g = lane >> 4;
    int hpar = m & 1, wloc = m >> 1;

    // ---- stage input tile: rows hblk-1..hblk+8, pix wblk-1..wblk+32 ----
    {
        const uint4* s4 = (const uint4*)in;
        uint4* d = (uint4*)&in_t[0][0][0];
        for (int c = tid; c < 2040; c += 256) {
            int row = c / 204;
            int rem = c - row * 204;
            int pix = rem / 6;
            int sub = rem - pix * 6;
            int gh = hblk - 1 + row, gw = wblk - 1 + pix;
            uint4 v = {0u, 0u, 0u, 0u};
            if ((unsigned)gh < (unsigned)H && (unsigned)gw < (unsigned)W)
                v = s4[((n * H + gh) * W + gw) * 6 + sub];
            d[(row * 34 + pix) * 7 + sub] = v;
        }
    }

    // per-lane per-step offsets: k-chunk kc = 4*s+g, tap = kc/6, ci8 = kc%6
    int aoff[14], boff[14];
    #pragma unroll
    for (int s = 0; s < 14; ++s) {
        int kc = 4 * s + g;
        int tap = kc / 6, ci8 = kc - tap * 6;
        int dr = tap / 3, ds = tap - 3 * dr;
        if (tap == 9) { dr = 0; ds = 0; }          // B is zeros there
        aoff[s] = ((hpar + dr) * 34 + (wloc + ds)) * 112 + ci8 * 16;
        boff[s] = tap * 4608 + ci8 * 16;           // + m*96 (+nt*1536) at use
    }
    int abase = hp * 2 * 34 * 112;
    const char* ib = (const char*)&in_t[0][0][0];
    const char* bp = (const char*)wp + m * 96;

    f32x4 acc[4][3];
    #pragma unroll
    for (int mt = 0; mt < 4; ++mt)
        #pragma unroll
        for (int nt = 0; nt < 3; ++nt)
            acc[mt][nt] = (f32x4){0.f, 0.f, 0.f, 0.f};

    __syncthreads();

    #pragma unroll
    for (int s = 0; s < 14; ++s) {
        f16x8 b0 = *(const f16x8*)(bp + boff[s]);
        f16x8 b1 = *(const f16x8*)(bp + boff[s] + 1536);
        f16x8 b2 = *(const f16x8*)(bp + boff[s] + 3072);
        f16x8 a[4];
        #pragma unroll
        for (int mt = 0; mt < 4; ++mt)
            a[mt] = *(const f16x8*)(ib + abase + aoff[s] + mt * 896);
        __builtin_amdgcn_s_setprio(1);
        #pragma unroll
        for (int mt = 0; mt < 4; ++mt) {
            acc[mt][0] = __builtin_amdgcn_mfma_f32_16x16x32_f16(a[mt], b0, acc[mt][0], 0, 0, 0);
            acc[mt][1] = __builtin_amdgcn_mfma_f32_16x16x32_f16(a[mt], b1, acc[mt][1], 0, 0, 0);
            acc[mt][2] = __builtin_amdgcn_mfma_f32_16x16x32_f16(a[mt], b2, acc[mt][2], 0, 0, 0);
        }
        __builtin_amdgcn_s_setprio(0);
    }

    // ---- epilogue: bias + leaky + 2x2 maxpool (within-lane) ----
    int hq = blockIdx.x * 4 + hp;
    #pragma unroll
    for (int nt = 0; nt < 3; ++nt) {
        int co = nt * 16 + m;
        float bb = bias[co];
        #pragma unroll
        for (int mt = 0; mt < 4; ++mt) {
            float pmax = -1e30f;
            #pragma unroll
            for (int j = 0; j < 4; ++j) {
                float v = acc[mt][nt][j] + bb;
                v = v > 0.f ? v : LEAKY * v;
                pmax = fmaxf(pmax, v);
            }
            int wq = blockIdx.y * 16 + mt * 4 + g;
            if (FINAL)
                ((float*)outv)[(((long)n * 48 + co) * HO + hq) * WO + wq] = pmax;
            else
                ((half_t*)outv)[((n * HO + hq) * WO + wq) * 48 + co] = (half_t)pmax;
        }
    }
}

// ===========================================================================
extern "C" void kernel_launch(void* const* d_in, const int* in_sizes, int n_in,
                              void* d_out, int out_size, void* d_ws, size_t ws_size,
                              hipStream_t stream)
{
    const float* x  = (const float*)d_in[0];
    const float* w1 = (const float*)d_in[1];
    const float* b1 = (const float*)d_in[2];
    const float* w2 = (const float*)d_in[3];
    const float* b2 = (const float*)d_in[4];
    const float* w3 = (const float*)d_in[5];
    const float* b3 = (const float*)d_in[6];
    const float* w4 = (const float*)d_in[7];
    const float* b4 = (const float*)d_in[8];

    half_t* Wb = (half_t*)d_ws;
    half_t* wp1  = Wb;                      // 1920 (pad 2048)
    half_t* wp2  = Wb + 2048;               // 23040 per layer
    half_t* wp3  = wp2 + 23040;
    half_t* wp4  = wp3 + 23040;
    half_t* act1 = wp4 + 23040;             // 8*256*256*48 = 25165824
    half_t* act2 = act1 + 25165824;         // 8*128*128*48 = 6291456
    half_t* act3 = act2 + 6291456;          // 8*64*64*48   = 1572864

    prep_w_k<<<dim3(139), 512, 0, stream>>>(w1, w2, w3, w4, wp1, wp2);

    // conv1: 3->48 @256x256
    conv1_mfma_k<<<dim3(16, 8, 8), 512, 0, stream>>>(x, wp1, b1, act1);
    // conv2: 48->48 @256 + pool -> 128
    convpool3_k<256, 256, false><<<dim3(32, 8, 8), 256, 0, stream>>>(act1, wp2, b2, act2);
    // conv3: 48->48 @128 + pool -> 64
    convpool3_k<128, 128, false><<<dim3(16, 4, 8), 256, 0, stream>>>(act2, wp3, b3, act3);
    // conv4: 48->48 @64 + pool -> 32, fp32 NCHW out
    convpool3_k<64, 64, true><<<dim3(8, 2, 8), 256, 0, stream>>>(act3, wp4, b4, d_out);
}

// Round 5
// 76.252 us; speedup vs baseline: 12.7061x; 1.0136x over previous
//
#include <hip/hip_runtime.h>
#include <hip/hip_bf16.h>

typedef _Float16 half_t;
typedef _Float16 f16x8 __attribute__((ext_vector_type(8)));
typedef float f32x4 __attribute__((ext_vector_type(4)));

#define LEAKY 0.1f

// ===========================================================================
// conv1 (3->48, 256x256, no pool) via MFMA; x-tile staged in LDS.
// Block: 512 thr = 8 waves; tile 16h x 32w. Out: NHWC-48 fp16.
// Also performs weight prep: per-block w1 transform into LDS (no global wp1),
// and blocks 0..134 write the global wp234 = [layer][tap(10)][co][ci] table.
// ===========================================================================
__global__ __launch_bounds__(512) void conv1_mfma_k(const float* __restrict__ x,
                                                    const float* __restrict__ w1,
                                                    const float* __restrict__ w2,
                                                    const float* __restrict__ w3,
                                                    const float* __restrict__ w4,
                                                    const float* __restrict__ bias,
                                                    half_t* __restrict__ wp234,
                                                    half_t* __restrict__ out)
{
    __shared__ alignas(16) half_t xt[3][18][36];    // rows hblk-1.., cols wblk-1..
    __shared__ alignas(16) half_t wlds[48][40];

    int tid = threadIdx.x;
    int n = blockIdx.z;
    int hblk = blockIdx.x * 16, wblk = blockIdx.y * 32;

    // ---- global wp234 prep (first 135 blocks, one elem/thread) ----
    {
        int bid = blockIdx.x + 16 * (blockIdx.y + 8 * blockIdx.z);
        int t2 = bid * 512 + tid;
        if (t2 < 3 * 23040) {
            int layer = t2 / 23040;
            int r = t2 % 23040;
            int tap = r / 2304;
            int r2 = r % 2304;
            int co = r2 / 48, ci = r2 % 48;
            const float* src = layer == 0 ? w2 : (layer == 1 ? w3 : w4);
            float v = 0.f;
            if (tap < 9) v = src[((co * 48 + ci) * 3 + tap / 3) * 3 + tap % 3];
            wp234[t2] = (half_t)v;
        }
    }
    // ---- per-block w1 transform into LDS: [co(48)][40], k=(dr*3+ds)*3+ci ----
    for (int t = tid; t < 1920; t += 512) {
        int co = t / 40, kk = t % 40;
        float v = 0.f;
        if (kk < 27) {
            int ci = kk % 3, tap = kk / 3, dr = tap / 3, ds = tap % 3;
            v = w1[((co * 3 + ci) * 3 + dr) * 3 + ds];
        }
        wlds[co][kk] = (half_t)v;
    }
    // ---- x tile ----
    for (int c = tid; c < 3 * 18 * 34; c += 512) {
        int ci = c / 612, rem = c % 612;
        int row = rem / 34, col = rem % 34;
        int gh = hblk - 1 + row, gw = wblk - 1 + col;
        float v = 0.f;
        if ((unsigned)gh < 256u && (unsigned)gw < 256u)
            v = x[((n * 3 + ci) * 256 + gh) * 256 + gw];
        xt[ci][row][col] = (half_t)v;
    }
    __syncthreads();

    int lane = tid & 63, wave = tid >> 6;
    int m = lane & 15, g = lane >> 4;
    int hpar = m & 1, wloc = m >> 1;
    int row0 = 2 * wave + hpar;

    // A fragments from xt: elem j of frag mt has k = g*8+j
    f16x8 afr[4];
    #pragma unroll
    for (int j = 0; j < 8; ++j) {
        int k = g * 8 + j;
        int tap = k / 3, ci = k - 3 * tap;
        int dr = tap / 3, ds = tap - 3 * dr;
        bool valid = k < 27;
        #pragma unroll
        for (int mt = 0; mt < 4; ++mt) {
            half_t v = (half_t)0.f;
            if (valid) v = xt[ci][row0 + dr][mt * 8 + wloc + ds];
            afr[mt][j] = v;
        }
    }

    const char* wb = (const char*)&wlds[0][0];
    f16x8 bfr[3];
    #pragma unroll
    for (int nt = 0; nt < 3; ++nt)
        bfr[nt] = *(const f16x8*)(wb + (nt * 16 + m) * 80 + g * 16);

    f32x4 acc[4][3];
    #pragma unroll
    for (int mt = 0; mt < 4; ++mt)
        #pragma unroll
        for (int nt = 0; nt < 3; ++nt) {
            f32x4 z = {0.f, 0.f, 0.f, 0.f};
            acc[mt][nt] = __builtin_amdgcn_mfma_f32_16x16x32_f16(afr[mt], bfr[nt], z, 0, 0, 0);
        }

    #pragma unroll
    for (int nt = 0; nt < 3; ++nt) {
        int co = nt * 16 + m;
        float bb = bias[co];
        #pragma unroll
        for (int mt = 0; mt < 4; ++mt) {
            #pragma unroll
            for (int j = 0; j < 4; ++j) {
                float v = acc[mt][nt][j] + bb;
                v = v > 0.f ? v : LEAKY * v;
                int h = hblk + 2 * wave + (j & 1);
                int w = wblk + mt * 8 + 2 * g + (j >> 1);
                out[((n * 256 + h) * 256 + w) * 48 + co] = (half_t)v;
            }
        }
    }
}

// ===========================================================================
// convpool (48->48, 3x3 pad1 + bias + leaky + 2x2 maxpool), single-phase K.
// Block: 256 thr = 4 waves; wave = 1 h-pair x (8*MT) w cols. Tile 8 rows.
// A: LDS in_t[10][8*MT+2][56-pad] (112 B/pixel). B: direct from global (L2).
// K = tap*48+ci, 432 real padded to 448 (tap 9 zeros) = 14 steps.
// MT=8 halves B-traffic per MFMA (128 FLOP/B) for the heavy conv2.
// ===========================================================================
template<int H, int W, int MT, bool FINAL>
__global__ __launch_bounds__(256, (MT == 8) ? 2 : 4)
void convpool4_k(const half_t* __restrict__ in,
                 const half_t* __restrict__ wp,
                 const float* __restrict__ bias,
                 void* __restrict__ outv)
{
    constexpr int HO = H / 2, WO = W / 2;
    constexpr int TC = 8 * MT + 2;              // tile cols incl. halo
    constexpr int NU4 = 10 * TC * 6;            // staged uint4 count

    __shared__ alignas(16) half_t in_t[10][TC][56];

    int tid = threadIdx.x;
    int n = blockIdx.z;
    int hblk = blockIdx.x * 8, wblk = blockIdx.y * (8 * MT);
    int lane = tid & 63, hp = tid >> 6;         // wave = h-pair (0..3)
    int m = lane & 15, g = lane >> 4;
    int hpar = m & 1, wloc = m >> 1;

    // ---- stage input tile: rows hblk-1..hblk+8, pix wblk-1..wblk+8*MT ----
    {
        const uint4* s4 = (const uint4*)in;
        uint4* d = (uint4*)&in_t[0][0][0];
        #pragma unroll
        for (int i = 0; i < (NU4 + 255) / 256; ++i) {
            int c = tid + i * 256;
            if (c < NU4) {
                int row = c / (TC * 6);
                int rem = c - row * (TC * 6);
                int pix = rem / 6;
                int sub = rem - pix * 6;
                int gh = hblk - 1 + row, gw = wblk - 1 + pix;
                uint4 v = {0u, 0u, 0u, 0u};
                if ((unsigned)gh < (unsigned)H && (unsigned)gw < (unsigned)W)
                    v = s4[((n * H + gh) * W + gw) * 6 + sub];
                d[(row * TC + pix) * 7 + sub] = v;
            }
        }
    }

    // per-lane per-step offsets: k-chunk kc = 4*s+g, tap = kc/6, ci8 = kc%6
    int aoff[14], boff[14];
    #pragma unroll
    for (int s = 0; s < 14; ++s) {
        int kc = 4 * s + g;
        int tap = kc / 6, ci8 = kc - tap * 6;
        int dr = tap / 3, ds = tap - 3 * dr;
        if (tap == 9) { dr = 0; ds = 0; }       // B is zeros there
        aoff[s] = ((hpar + dr) * TC + (wloc + ds)) * 112 + ci8 * 16;
        boff[s] = tap * 4608 + ci8 * 16;        // + m*96 (+nt*1536) at use
    }
    int abase = hp * 2 * TC * 112;
    const char* ib = (const char*)&in_t[0][0][0];
    const char* bp = (const char*)wp + m * 96;

    f32x4 acc[MT][3];
    #pragma unroll
    for (int mt = 0; mt < MT; ++mt)
        #pragma unroll
        for (int nt = 0; nt < 3; ++nt)
            acc[mt][nt] = (f32x4){0.f, 0.f, 0.f, 0.f};

    __syncthreads();

    #pragma unroll
    for (int s = 0; s < 14; ++s) {
        f16x8 b0 = *(const f16x8*)(bp + boff[s]);
        f16x8 b1 = *(const f16x8*)(bp + boff[s] + 1536);
        f16x8 b2 = *(const f16x8*)(bp + boff[s] + 3072);
        f16x8 a[MT];
        #pragma unroll
        for (int mt = 0; mt < MT; ++mt)
            a[mt] = *(const f16x8*)(ib + abase + aoff[s] + mt * 896);
        __builtin_amdgcn_s_setprio(1);
        #pragma unroll
        for (int mt = 0; mt < MT; ++mt) {
            acc[mt][0] = __builtin_amdgcn_mfma_f32_16x16x32_f16(a[mt], b0, acc[mt][0], 0, 0, 0);
            acc[mt][1] = __builtin_amdgcn_mfma_f32_16x16x32_f16(a[mt], b1, acc[mt][1], 0, 0, 0);
            acc[mt][2] = __builtin_amdgcn_mfma_f32_16x16x32_f16(a[mt], b2, acc[mt][2], 0, 0, 0);
        }
        __builtin_amdgcn_s_setprio(0);
    }

    // ---- epilogue: bias + leaky + 2x2 maxpool (within-lane) ----
    int hq = blockIdx.x * 4 + hp;
    #pragma unroll
    for (int nt = 0; nt < 3; ++nt) {
        int co = nt * 16 + m;
        float bb = bias[co];
        #pragma unroll
        for (int mt = 0; mt < MT; ++mt) {
            float pmax = -1e30f;
            #pragma unroll
            for (int j = 0; j < 4; ++j) {
                float v = acc[mt][nt][j] + bb;
                v = v > 0.f ? v : LEAKY * v;
                pmax = fmaxf(pmax, v);
            }
            int wq = blockIdx.y * (4 * MT) + mt * 4 + g;
            if (FINAL)
                ((float*)outv)[(((long)n * 48 + co) * HO + hq) * WO + wq] = pmax;
            else
                ((half_t*)outv)[((n * HO + hq) * WO + wq) * 48 + co] = (half_t)pmax;
        }
    }
}

// ===========================================================================
extern "C" void kernel_launch(void* const* d_in, const int* in_sizes, int n_in,
                              void* d_out, int out_size, void* d_ws, size_t ws_size,
                              hipStream_t stream)
{
    const float* x  = (const float*)d_in[0];
    const float* w1 = (const float*)d_in[1];
    const float* b1 = (const float*)d_in[2];
    const float* w2 = (const float*)d_in[3];
    const float* b2 = (const float*)d_in[4];
    const float* w3 = (const float*)d_in[5];
    const float* b3 = (const float*)d_in[6];
    const float* w4 = (const float*)d_in[7];
    const float* b4 = (const float*)d_in[8];

    half_t* Wb = (half_t*)d_ws;
    half_t* wp2  = Wb;                      // [3][10][48][48] = 69120 halfs
    half_t* wp3  = wp2 + 23040;
    half_t* wp4  = wp3 + 23040;
    half_t* act1 = Wb + 69120;              // 8*256*256*48 = 25165824
    half_t* act2 = act1 + 25165824;         // 8*128*128*48 = 6291456
    half_t* act3 = act2 + 6291456;          // 8*64*64*48   = 1572864

    // conv1: 3->48 @256x256 (also preps wp234 table)
    conv1_mfma_k<<<dim3(16, 8, 8), 512, 0, stream>>>(x, w1, w2, w3, w4, b1, wp2, act1);
    // conv2: 48->48 @256 + pool -> 128  (MT=8: 64-wide wave tiles)
    convpool4_k<256, 256, 8, false><<<dim3(32, 4, 8), 256, 0, stream>>>(act1, wp2, b2, act2);
    // conv3: 48->48 @128 + pool -> 64
    convpool4_k<128, 128, 4, false><<<dim3(16, 4, 8), 256, 0, stream>>>(act2, wp3, b3, act3);
    // conv4: 48->48 @64 + pool -> 32, fp32 NCHW out
    convpool4_k<64, 64, 4, true><<<dim3(8, 2, 8), 256, 0, stream>>>(act3, wp4, b4, d_out);
}

// Round 6
// 59.060 us; speedup vs baseline: 16.4046x; 1.2911x over previous
//
#include <hip/hip_runtime.h>
#include <hip/hip_bf16.h>

typedef _Float16 half_t;
typedef _Float16 f16x8 __attribute__((ext_vector_type(8)));
typedef _Float16 f16x4 __attribute__((ext_vector_type(4)));
typedef float f32x4 __attribute__((ext_vector_type(4)));

#define LEAKY 0.1f

// ===========================================================================
// prep: wp234 = [layer(3)][tap(10)][co(48)][ci(48)], tap 9 = zeros (69120 h)
// ===========================================================================
__global__ __launch_bounds__(512) void prep_w_k(const float* __restrict__ w2,
                                                const float* __restrict__ w3,
                                                const float* __restrict__ w4,
                                                half_t* __restrict__ wp234)
{
    int t = blockIdx.x * 512 + threadIdx.x;
    if (t >= 3 * 23040) return;
    int layer = t / 23040;
    int r = t % 23040;
    int tap = r / 2304;
    int r2 = r % 2304;
    int co = r2 / 48, ci = r2 % 48;
    const float* src = layer == 0 ? w2 : (layer == 1 ? w3 : w4);
    float v = 0.f;
    if (tap < 9) v = src[((co * 48 + ci) * 3 + tap / 3) * 3 + tap % 3];
    wp234[t] = (half_t)v;
}

// ===========================================================================
// Fused conv1(3->48) + conv2(48->48) + bias/leaky + 2x2 maxpool.
// Block: 512 thr = 8 waves; conv2-input tile 16 rows x 32 cols -> pooled 8x16.
// conv1 computes the 18x34 halo tile DIRECTLY into LDS in_t[px][56] via
// swapped-operand MFMA (a=weights, b=pixels): lane holds 4 consecutive couts
// at one pixel -> ds_write_b64 in conv2's native A layout.
// conv2: K = tap*48+ci (432 pad 448, 14 steps), A from LDS, B from global L2.
// ===========================================================================
__global__ __launch_bounds__(512, 4) void conv12_k(const float* __restrict__ x,
                                                   const float* __restrict__ w1,
                                                   const float* __restrict__ b1,
                                                   const half_t* __restrict__ wp2,
                                                   const float* __restrict__ b2,
                                                   half_t* __restrict__ out)
{
    __shared__ alignas(16) half_t in_t[624 * 56];   // conv1 out [px = row*34+col][co56]
    __shared__ alignas(16) half_t xt[21][36][4];    // x patch, ci-minor (pad 4)
    __shared__ alignas(16) half_t w1t[48 * 40];     // [co][k40], k=(tap)*3+ci, 27..39=0

    const int tid = threadIdx.x;
    const int n = blockIdx.z;
    const int hblk = blockIdx.x * 16, wblk = blockIdx.y * 32;
    const int lane = tid & 63, hp = tid >> 6;       // 8 waves = h-pairs 0..7
    const int m = lane & 15, g = lane >> 4;

    // ---- stage w1 transform: [co][40] ----
    for (int t = tid; t < 1920; t += 512) {
        int co = t / 40, kk = t % 40;
        float v = 0.f;
        if (kk < 27) {
            int tap = kk / 3, ci = kk % 3;
            v = w1[((co * 3 + ci) * 3 + tap / 3) * 3 + tap % 3];
        }
        w1t[t] = (half_t)v;
    }
    // ---- stage x patch rows hblk-2..hblk+18 (21), cols wblk-2..wblk+33 (36) ----
    for (int c = tid; c < 2268; c += 512) {
        int ci = c / 756, rem = c % 756;
        int row = rem / 36, col = rem % 36;
        int gh = hblk - 2 + row, gw = wblk - 2 + col;
        float v = 0.f;
        if ((unsigned)gh < 256u && (unsigned)gw < 256u)
            v = x[((n * 3 + ci) * 256 + gh) * 256 + gw];
        xt[row][col][ci] = (half_t)v;
    }
    __syncthreads();

    // =================== conv1 phase ===================
    // per-lane x-read offsets for k = g*8+j (tap = k/3, ci = k%3)
    int xoff[8];
    #pragma unroll
    for (int j = 0; j < 8; ++j) {
        int k = g * 8 + j;
        int tap = k / 3, ci = k - 3 * tap;
        int dr = tap / 3, ds = tap - 3 * dr;
        xoff[j] = (k < 27) ? ((dr * 36 + ds) * 8 + ci * 2) : 0;   // k>=27: weight=0
    }
    // weight fragments (a-operand: lane&15 = co within nt-group) + bias
    f16x8 wf[3];
    float bb1[12];
    #pragma unroll
    for (int nt = 0; nt < 3; ++nt) {
        wf[nt] = *(const f16x8*)((const char*)w1t + (nt * 16 + m) * 80 + g * 16);
        #pragma unroll
        for (int j = 0; j < 4; ++j) bb1[nt * 4 + j] = b1[nt * 16 + 4 * g + j];
    }
    const char* xtb = (const char*)&xt[0][0][0];
    // 39 pixel-tiles of 16 cover px 0..623 (612..623 = slop, harmless)
    for (int t = hp; t < 39; t += 8) {
        int px = t * 16 + m;
        int row = px / 34, col = px - row * 34;
        int pxb = (row * 36 + col) * 8;
        f16x8 pf;
        #pragma unroll
        for (int j = 0; j < 8; ++j)
            pf[j] = *(const half_t*)(xtb + pxb + xoff[j]);
        // conv2 zero-padding: conv1 "output" outside the image must be 0
        bool inb = ((unsigned)(hblk - 1 + row) < 256u) && ((unsigned)(wblk - 1 + col) < 256u);
        #pragma unroll
        for (int nt = 0; nt < 3; ++nt) {
            f32x4 d = {0.f, 0.f, 0.f, 0.f};
            d = __builtin_amdgcn_mfma_f32_16x16x32_f16(wf[nt], pf, d, 0, 0, 0);
            f16x4 o;
            #pragma unroll
            for (int j = 0; j < 4; ++j) {
                float v = d[j] + bb1[nt * 4 + j];
                v = v > 0.f ? v : LEAKY * v;
                o[j] = inb ? (half_t)v : (half_t)0.f;
            }
            *(f16x4*)(&in_t[px * 56 + nt * 16 + 4 * g]) = o;      // ds_write_b64
        }
    }
    __syncthreads();

    // =================== conv2 phase ===================
    const int hpar = m & 1, wloc = m >> 1;
    const int abase = hp * 2 * 34 * 112;
    const char* ib = (const char*)&in_t[0];
    const char* bp = (const char*)wp2 + m * 96;

    f32x4 acc[4][3];
    #pragma unroll
    for (int mt = 0; mt < 4; ++mt)
        #pragma unroll
        for (int nt = 0; nt < 3; ++nt)
            acc[mt][nt] = (f32x4){0.f, 0.f, 0.f, 0.f};

    #pragma unroll
    for (int s = 0; s < 14; ++s) {
        int kc = 4 * s + g;
        int tap = kc / 6, ci8 = kc - tap * 6;
        int dr = tap / 3, ds = tap - 3 * dr;
        if (tap == 9) { dr = 0; ds = 0; }           // B is zeros there
        int aoff = ((hpar + dr) * 34 + (wloc + ds)) * 112 + ci8 * 16;
        int boff = tap * 4608 + ci8 * 16;
        f16x8 b0 = *(const f16x8*)(bp + boff);
        f16x8 b1f = *(const f16x8*)(bp + boff + 1536);
        f16x8 b2f = *(const f16x8*)(bp + boff + 3072);
        f16x8 a[4];
        #pragma unroll
        for (int mt = 0; mt < 4; ++mt)
            a[mt] = *(const f16x8*)(ib + abase + aoff + mt * 896);
        __builtin_amdgcn_s_setprio(1);
        #pragma unroll
        for (int mt = 0; mt < 4; ++mt) {
            acc[mt][0] = __builtin_amdgcn_mfma_f32_16x16x32_f16(a[mt], b0, acc[mt][0], 0, 0, 0);
            acc[mt][1] = __builtin_amdgcn_mfma_f32_16x16x32_f16(a[mt], b1f, acc[mt][1], 0, 0, 0);
            acc[mt][2] = __builtin_amdgcn_mfma_f32_16x16x32_f16(a[mt], b2f, acc[mt][2], 0, 0, 0);
        }
        __builtin_amdgcn_s_setprio(0);
    }

    // ---- epilogue: bias + leaky + 2x2 maxpool -> act2 NHWC-48 ----
    int hq = blockIdx.x * 8 + hp;
    #pragma unroll
    for (int nt = 0; nt < 3; ++nt) {
        int co = nt * 16 + m;
        float bb = b2[co];
        #pragma unroll
        for (int mt = 0; mt < 4; ++mt) {
            float pmax = -1e30f;
            #pragma unroll
            for (int j = 0; j < 4; ++j) {
                float v = acc[mt][nt][j] + bb;
                v = v > 0.f ? v : LEAKY * v;
                pmax = fmaxf(pmax, v);
            }
            int wq = blockIdx.y * 16 + mt * 4 + g;
            out[((n * 128 + hq) * 128 + wq) * 48 + co] = (half_t)pmax;
        }
    }
}

// ===========================================================================
// convpool (48->48, 3x3 pad1 + bias + leaky + 2x2 maxpool), single-phase K.
// Block: 256 thr = 4 waves; wave = 1 h-pair x (8*MT) cols. A: LDS; B: global.
// ===========================================================================
template<int H, int W, int MT, bool FINAL>
__global__ __launch_bounds__(256, 4)
void convpool4_k(const half_t* __restrict__ in,
                 const half_t* __restrict__ wp,
                 const float* __restrict__ bias,
                 void* __restrict__ outv)
{
    constexpr int HO = H / 2, WO = W / 2;
    constexpr int TC = 8 * MT + 2;
    constexpr int NU4 = 10 * TC * 6;

    __shared__ alignas(16) half_t in_t[10][TC][56];

    int tid = threadIdx.x;
    int n = blockIdx.z;
    int hblk = blockIdx.x * 8, wblk = blockIdx.y * (8 * MT);
    int lane = tid & 63, hp = tid >> 6;
    int m = lane & 15, g = lane >> 4;
    int hpar = m & 1, wloc = m >> 1;

    {
        const uint4* s4 = (const uint4*)in;
        uint4* d = (uint4*)&in_t[0][0][0];
        #pragma unroll
        for (int i = 0; i < (NU4 + 255) / 256; ++i) {
            int c = tid + i * 256;
            if (c < NU4) {
                int row = c / (TC * 6);
                int rem = c - row * (TC * 6);
                int pix = rem / 6;
                int sub = rem - pix * 6;
                int gh = hblk - 1 + row, gw = wblk - 1 + pix;
                uint4 v = {0u, 0u, 0u, 0u};
                if ((unsigned)gh < (unsigned)H && (unsigned)gw < (unsigned)W)
                    v = s4[((n * H + gh) * W + gw) * 6 + sub];
                d[(row * TC + pix) * 7 + sub] = v;
            }
        }
    }

    int abase = hp * 2 * TC * 112;
    const char* ib = (const char*)&in_t[0][0][0];
    const char* bp = (const char*)wp + m * 96;

    f32x4 acc[MT][3];
    #pragma unroll
    for (int mt = 0; mt < MT; ++mt)
        #pragma unroll
        for (int nt = 0; nt < 3; ++nt)
            acc[mt][nt] = (f32x4){0.f, 0.f, 0.f, 0.f};

    __syncthreads();

    #pragma unroll
    for (int s = 0; s < 14; ++s) {
        int kc = 4 * s + g;
        int tap = kc / 6, ci8 = kc - tap * 6;
        int dr = tap / 3, ds = tap - 3 * dr;
        if (tap == 9) { dr = 0; ds = 0; }
        int aoff = ((hpar + dr) * TC + (wloc + ds)) * 112 + ci8 * 16;
        int boff = tap * 4608 + ci8 * 16;
        f16x8 b0 = *(const f16x8*)(bp + boff);
        f16x8 b1 = *(const f16x8*)(bp + boff + 1536);
        f16x8 b2 = *(const f16x8*)(bp + boff + 3072);
        f16x8 a[MT];
        #pragma unroll
        for (int mt = 0; mt < MT; ++mt)
            a[mt] = *(const f16x8*)(ib + abase + aoff + mt * 896);
        __builtin_amdgcn_s_setprio(1);
        #pragma unroll
        for (int mt = 0; mt < MT; ++mt) {
            acc[mt][0] = __builtin_amdgcn_mfma_f32_16x16x32_f16(a[mt], b0, acc[mt][0], 0, 0, 0);
            acc[mt][1] = __builtin_amdgcn_mfma_f32_16x16x32_f16(a[mt], b1, acc[mt][1], 0, 0, 0);
            acc[mt][2] = __builtin_amdgcn_mfma_f32_16x16x32_f16(a[mt], b2, acc[mt][2], 0, 0, 0);
        }
        __builtin_amdgcn_s_setprio(0);
    }

    int hq = blockIdx.x * 4 + hp;
    #pragma unroll
    for (int nt = 0; nt < 3; ++nt) {
        int co = nt * 16 + m;
        float bb = bias[co];
        #pragma unroll
        for (int mt = 0; mt < MT; ++mt) {
            float pmax = -1e30f;
            #pragma unroll
            for (int j = 0; j < 4; ++j) {
                float v = acc[mt][nt][j] + bb;
                v = v > 0.f ? v : LEAKY * v;
                pmax = fmaxf(pmax, v);
            }
            int wq = blockIdx.y * (4 * MT) + mt * 4 + g;
            if (FINAL)
                ((float*)outv)[(((long)n * 48 + co) * HO + hq) * WO + wq] = pmax;
            else
                ((half_t*)outv)[((n * HO + hq) * WO + wq) * 48 + co] = (half_t)pmax;
        }
    }
}

// ===========================================================================
extern "C" void kernel_launch(void* const* d_in, const int* in_sizes, int n_in,
                              void* d_out, int out_size, void* d_ws, size_t ws_size,
                              hipStream_t stream)
{
    const float* x  = (const float*)d_in[0];
    const float* w1 = (const float*)d_in[1];
    const float* b1 = (const float*)d_in[2];
    const float* w2 = (const float*)d_in[3];
    const float* b2 = (const float*)d_in[4];
    const float* w3 = (const float*)d_in[5];
    const float* b3 = (const float*)d_in[6];
    const float* w4 = (const float*)d_in[7];
    const float* b4 = (const float*)d_in[8];

    half_t* Wb = (half_t*)d_ws;
    half_t* wp2  = Wb;                      // [3][10][48][48] = 69120 halfs
    half_t* wp3  = wp2 + 23040;
    half_t* wp4  = wp3 + 23040;
    half_t* act2 = Wb + 69120;              // 8*128*128*48 = 6291456
    half_t* act3 = act2 + 6291456;          // 8*64*64*48   = 1572864

    prep_w_k<<<dim3(135), 512, 0, stream>>>(w2, w3, w4, wp2);

    // fused conv1+conv2: 3->48->48 @256 + pool -> act2 (128x128 NHWC-48)
    conv12_k<<<dim3(16, 8, 8), 512, 0, stream>>>(x, w1, b1, wp2, b2, act2);
    // conv3: 48->48 @128 + pool -> 64
    convpool4_k<128, 128, 4, false><<<dim3(16, 4, 8), 256, 0, stream>>>(act2, wp3, b3, act3);
    // conv4: 48->48 @64 + pool -> 32, fp32 NCHW out
    convpool4_k<64, 64, 2, true><<<dim3(8, 4, 8), 256, 0, stream>>>(act3, wp4, b4, d_out);
}